// Round 2
// baseline (415.318 us; speedup 1.0000x reference)
//
#include <hip/hip_runtime.h>

// VQ-VAE forward: x [64,64,32,32] f32 (NCHW, C==D), weight [512,64] f32.
// d_out: loss (1) | q_out (4194304, NCHW) | encodings (33554432, [N,K]).
// N = 65536 rows, D = 64, K = 512.
//
// R2: split K across 4 waves/block (each wave scans 128 codes for the same
// 64 rows) -> 1024 blocks x 4 waves = 16 waves/CU (was 4). Cross-wave argmin
// reduce in LDS, tie-break = lowest k (wave order + strict <).

#define NROWS 65536
#define DIM 64
#define KCODES 512
#define HW 1024
#define TPB 256
#define RPB 64                      // rows per block
#define NBLOCKS (NROWS / RPB)       // 1024
#define KSLICE (KCODES / 4)         // 128 codes per wave

typedef float v2f __attribute__((ext_vector_type(2)));
typedef float v4f __attribute__((ext_vector_type(4)));

__global__ __launch_bounds__(TPB) void vq_main(
    const float* __restrict__ x,
    const float* __restrict__ w,
    float* __restrict__ out,
    float* __restrict__ partial)
{
    __shared__ float e2[KCODES];
    __shared__ float bestv[4][RPB];
    __shared__ int   bidxv[4][RPB];
    __shared__ int   idx_final[RPB];
    __shared__ float lsum_lds[4];

    const int t    = threadIdx.x;
    const int lane = t & 63;          // row within block
    const int wv   = t >> 6;          // wave id -> K slice
    const int n0   = blockIdx.x * RPB;
    const int b    = n0 >> 10;        // 1024 % 64 == 0: no straddle
    const int hw   = (n0 & 1023) + lane;
    const int kbase = wv * KSLICE;

    // ---- e2 for this wave's slice: each lane does 2 codes.
    // Mirror XLA: elementwise mul then add (no fma contraction).
    #pragma unroll
    for (int c = 0; c < 2; ++c) {
        const int k = kbase + lane * 2 + c;
        const float* wr = w + k * DIM;
        float s = 0.0f;
        for (int d = 0; d < DIM; ++d) s = __fadd_rn(s, __fmul_rn(wr[d], wr[d]));
        e2[k] = s;
    }

    // ---- x row for this lane (all 4 waves load the same 64 rows; L2-hot).
    v2f xv[DIM / 2];
    {
        const float* xb = x + (size_t)(b * DIM) * HW + hw;
        #pragma unroll
        for (int i = 0; i < DIM / 2; ++i) {
            xv[i][0] = xb[(size_t)(2 * i) * HW];
            xv[i][1] = xb[(size_t)(2 * i + 1) * HW];
        }
    }

    float x2 = 0.0f;
    #pragma unroll
    for (int i = 0; i < DIM / 2; ++i) {
        x2 = __fadd_rn(x2, __fmul_rn(xv[i][0], xv[i][0]));
        x2 = __fadd_rn(x2, __fmul_rn(xv[i][1], xv[i][1]));
    }

    __syncthreads();   // e2 slice written by own wave only, but keep it simple

    // ---- argmin over this wave's 128 codes; 4 code-accumulators.
    const v2f* w2 = (const v2f*)w;
    float best = 3.4e38f;
    int   bidx = kbase;
    for (int k0 = kbase; k0 < kbase + KSLICE; k0 += 4) {
        v2f a0 = {0.f, 0.f}, a1 = {0.f, 0.f}, a2 = {0.f, 0.f}, a3 = {0.f, 0.f};
        const v2f* wr0 = w2 + (k0 + 0) * (DIM / 2);
        const v2f* wr1 = w2 + (k0 + 1) * (DIM / 2);
        const v2f* wr2 = w2 + (k0 + 2) * (DIM / 2);
        const v2f* wr3 = w2 + (k0 + 3) * (DIM / 2);
        #pragma unroll
        for (int i = 0; i < DIM / 2; ++i) {
            const v2f xvi = xv[i];
            a0 += xvi * wr0[i];          // v_pk_fma_f32, SGPR-broadcast w
            a1 += xvi * wr1[i];
            a2 += xvi * wr2[i];
            a3 += xvi * wr3[i];
        }
        const v4f e4 = *(const v4f*)&e2[k0];   // ds_read_b128 broadcast
        float dots[4];
        dots[0] = a0[0] + a0[1];
        dots[1] = a1[0] + a1[1];
        dots[2] = a2[0] + a2[1];
        dots[3] = a3[0] + a3[1];
        #pragma unroll
        for (int c = 0; c < 4; ++c) {
            const float dist = __fsub_rn(__fadd_rn(x2, e4[c]),
                                         __fmul_rn(2.0f, dots[c]));
            if (dist < best) { best = dist; bidx = k0 + c; }   // first-min
        }
    }

    bestv[wv][lane] = best;
    bidxv[wv][lane] = bidx;
    __syncthreads();

    // ---- cross-wave argmin (wave 0 lanes), ascending wave = ascending k:
    if (t < RPB) {
        float bb = bestv[0][t];
        int   bi = bidxv[0][t];
        #pragma unroll
        for (int v = 1; v < 4; ++v) {
            const float c = bestv[v][t];
            if (c < bb) { bb = c; bi = bidxv[v][t]; }  // strict <: lower k wins ties
        }
        idx_final[t] = bi;
    }
    __syncthreads();

    // ---- epilogue: each wave covers d-slice [wv*16, wv*16+16) for its row.
    const int myidx = idx_final[lane];
    const float* wrow = w + myidx * DIM;
    float* q = out + 1;
    float lsum = 0.0f;
    #pragma unroll
    for (int j = 0; j < 8; ++j) {
        const int d = wv * 16 + 2 * j;
        const v2f wp = *(const v2f*)(wrow + d);   // per-lane gather, L2-hot
        const float xd0 = xv[d >> 1][0];
        const float xd1 = xv[d >> 1][1];
        const float df0 = __fsub_rn(wp[0], xd0);
        const float df1 = __fsub_rn(wp[1], xd1);
        lsum = __fadd_rn(lsum, __fmul_rn(df0, df0));
        lsum = __fadd_rn(lsum, __fmul_rn(df1, df1));
        q[(size_t)(b * DIM + d) * HW + hw]       = wp[0];   // coalesced per d
        q[(size_t)(b * DIM + d + 1) * HW + hw]   = wp[1];
    }

    // ---- loss reduction
    #pragma unroll
    for (int off = 32; off; off >>= 1) lsum += __shfl_down(lsum, off, 64);
    if (lane == 0) lsum_lds[wv] = lsum;
    __syncthreads();
    if (t == 0)
        partial[blockIdx.x] = ((lsum_lds[0] + lsum_lds[1]) +
                               (lsum_lds[2] + lsum_lds[3]));

    // ---- one-hot: block slab = 64 rows x 512 = 8192 float4, coalesced.
    float* enc = out + 1 + (size_t)NROWS * DIM;
    v4f* enc4 = (v4f*)(enc + (size_t)n0 * KCODES);
    for (int i = t; i < RPB * KCODES / 4; i += TPB) {
        const int row = i >> 7;           // i / 128
        const int j4  = (i & 127) * 4;
        const int fi  = idx_final[row];
        v4f o;
        o[0] = (fi == j4 + 0) ? 1.0f : 0.0f;
        o[1] = (fi == j4 + 1) ? 1.0f : 0.0f;
        o[2] = (fi == j4 + 2) ? 1.0f : 0.0f;
        o[3] = (fi == j4 + 3) ? 1.0f : 0.0f;
        enc4[i] = o;
    }
}

__global__ __launch_bounds__(256) void vq_final(
    const float* __restrict__ partial, float* __restrict__ out)
{
    __shared__ float s[256];
    const int t = threadIdx.x;
    s[t] = (partial[t] + partial[t + 256]) + (partial[t + 512] + partial[t + 768]);
    __syncthreads();
    for (int off = 128; off; off >>= 1) {
        if (t < off) s[t] += s[t + off];
        __syncthreads();
    }
    if (t == 0) {
        const float m = s[0] / 4194304.0f;          // mean over B*H*W*D
        out[0] = __fadd_rn(m, __fmul_rn(0.25f, m)); // z_q + 0.25*z_e
    }
}

extern "C" void kernel_launch(void* const* d_in, const int* in_sizes, int n_in,
                              void* d_out, int out_size, void* d_ws, size_t ws_size,
                              hipStream_t stream) {
    const float* x = (const float*)d_in[0];
    const float* w = (const float*)d_in[1];
    float* out     = (float*)d_out;
    float* partial = (float*)d_ws;        // 1024 floats of scratch

    vq_main<<<NBLOCKS, TPB, 0, stream>>>(x, w, out, partial);
    vq_final<<<1, 256, 0, stream>>>(partial, out);
}

// Round 3
// 254.907 us; speedup vs baseline: 1.6293x; 1.6293x over previous
//
#include <hip/hip_runtime.h>

// VQ-VAE forward: x [64,64,32,32] f32 (NCHW, C==D), weight [512,64] f32.
// d_out: loss (1) | q_out (4194304, NCHW) | encodings (33554432, [N,K]).
// N = 65536 rows, D = 64, K = 512.
//
// R3: R2 structure (4-way K split, 16 waves/CU) + readfirstlane so the K-loop
// is wave-uniform in the compiler's eyes -> w loads are s_load broadcasts
// (scalar pipe) like R1, not per-lane VMEM (R2's regression: SGPR 112->32).
// enc written as aligned float4 zero-fill + scatter of ones (out+1 misalign
// handled by 3-float peel / 1-float tail per 128KB slab).

#define NROWS 65536
#define DIM 64
#define KCODES 512
#define HW 1024
#define TPB 256
#define RPB 64                      // rows per block
#define NBLOCKS (NROWS / RPB)       // 1024
#define NWAVES 4
#define KSLICE (KCODES / NWAVES)    // 128 codes per wave

typedef float v2f __attribute__((ext_vector_type(2)));
typedef float v4f __attribute__((ext_vector_type(4)));

__global__ __launch_bounds__(TPB) void vq_main(
    const float* __restrict__ x,
    const float* __restrict__ w,
    float* __restrict__ out,
    float* __restrict__ partial)
{
    __shared__ __align__(16) float e2[KCODES];
    __shared__ float bestv[NWAVES][RPB];
    __shared__ int   bidxv[NWAVES][RPB];
    __shared__ int   idx_final[RPB];
    __shared__ float lsum_lds[NWAVES];

    const int t    = threadIdx.x;
    const int lane = t & 63;          // row within block
    // wave id, forced into an SGPR so everything derived from it scalarizes:
    const int wvu  = __builtin_amdgcn_readfirstlane(t >> 6);
    const int n0   = blockIdx.x * RPB;
    const int b    = n0 >> 10;        // 1024 % 64 == 0: no straddle
    const int hw   = (n0 & 1023) + lane;
    const int kbase = wvu * KSLICE;   // scalar

    // ---- e2[k]: each thread does 2 codes (512 total). Mirror XLA:
    // elementwise mul then add (no fma contraction), d ascending.
    #pragma unroll
    for (int c = 0; c < 2; ++c) {
        const int k = t * 2 + c;
        const v2f* wr = (const v2f*)(w + k * DIM);
        float s = 0.0f;
        #pragma unroll
        for (int i = 0; i < DIM / 2; ++i) {
            s = __fadd_rn(s, __fmul_rn(wr[i][0], wr[i][0]));
            s = __fadd_rn(s, __fmul_rn(wr[i][1], wr[i][1]));
        }
        e2[k] = s;
    }

    // ---- x row for this lane (all 4 waves load the same 64 rows; L1/L2-hot).
    v2f xv[DIM / 2];
    {
        const float* xb = x + (size_t)(b * DIM) * HW + hw;
        #pragma unroll
        for (int i = 0; i < DIM / 2; ++i) {
            xv[i][0] = xb[(size_t)(2 * i) * HW];
            xv[i][1] = xb[(size_t)(2 * i + 1) * HW];
        }
    }

    float x2 = 0.0f;
    #pragma unroll
    for (int i = 0; i < DIM / 2; ++i) {
        x2 = __fadd_rn(x2, __fmul_rn(xv[i][0], xv[i][0]));
        x2 = __fadd_rn(x2, __fmul_rn(xv[i][1], xv[i][1]));
    }

    __syncthreads();   // e2 ready

    // ---- argmin over this wave's 128 codes; 4 code rows in flight.
    // k0 is scalar -> w row pointers are SGPRs -> s_load broadcast (scalar
    // pipe overlaps the v_pk_fma stream).
    const v2f* w2 = (const v2f*)w;
    float best = 3.4e38f;
    int   bidx = kbase;
    for (int k0 = kbase; k0 < kbase + KSLICE; k0 += 4) {
        v2f a0 = {0.f, 0.f}, a1 = {0.f, 0.f}, a2 = {0.f, 0.f}, a3 = {0.f, 0.f};
        const v2f* wr0 = w2 + (k0 + 0) * (DIM / 2);
        const v2f* wr1 = w2 + (k0 + 1) * (DIM / 2);
        const v2f* wr2 = w2 + (k0 + 2) * (DIM / 2);
        const v2f* wr3 = w2 + (k0 + 3) * (DIM / 2);
        #pragma unroll
        for (int i = 0; i < DIM / 2; ++i) {
            const v2f xvi = xv[i];
            a0 += xvi * wr0[i];          // v_pk_fma_f32, SGPR-broadcast w
            a1 += xvi * wr1[i];
            a2 += xvi * wr2[i];
            a3 += xvi * wr3[i];
        }
        const v4f e4 = *(const v4f*)&e2[k0];   // ds_read_b128, same-addr broadcast
        float dots[4];
        dots[0] = a0[0] + a0[1];
        dots[1] = a1[0] + a1[1];
        dots[2] = a2[0] + a2[1];
        dots[3] = a3[0] + a3[1];
        #pragma unroll
        for (int c = 0; c < 4; ++c) {
            const float dist = __fsub_rn(__fadd_rn(x2, e4[c]),
                                         __fmul_rn(2.0f, dots[c]));
            if (dist < best) { best = dist; bidx = k0 + c; }   // first-min
        }
    }

    bestv[wvu][lane] = best;
    bidxv[wvu][lane] = bidx;
    __syncthreads();

    // ---- cross-wave argmin (wave 0), ascending wave = ascending k:
    if (t < RPB) {
        float bb = bestv[0][t];
        int   bi = bidxv[0][t];
        #pragma unroll
        for (int v = 1; v < NWAVES; ++v) {
            const float c = bestv[v][t];
            if (c < bb) { bb = c; bi = bidxv[v][t]; }  // strict <: lower k wins
        }
        idx_final[t] = bi;
    }
    __syncthreads();

    // ---- epilogue: wave wvu covers d-slice [wvu*16, wvu*16+16) for its row.
    const int myidx = idx_final[lane];
    const float* wrow = w + myidx * DIM;
    float* q = out + 1;
    float lsum = 0.0f;
    #pragma unroll
    for (int j = 0; j < 8; ++j) {
        const int d = wvu * 16 + 2 * j;
        const v2f wp = *(const v2f*)(wrow + d);   // per-lane gather, cache-hot
        const float xd0 = xv[d >> 1][0];
        const float xd1 = xv[d >> 1][1];
        const float df0 = __fsub_rn(wp[0], xd0);
        const float df1 = __fsub_rn(wp[1], xd1);
        lsum = __fadd_rn(lsum, __fmul_rn(df0, df0));
        lsum = __fadd_rn(lsum, __fmul_rn(df1, df1));
        q[(size_t)(b * DIM + d) * HW + hw]       = wp[0];
        q[(size_t)(b * DIM + d + 1) * HW + hw]   = wp[1];
    }

    // ---- loss reduction
    #pragma unroll
    for (int off = 32; off; off >>= 1) lsum += __shfl_down(lsum, off, 64);
    if (lane == 0) lsum_lds[wvu] = lsum;
    __syncthreads();
    if (t == 0)
        partial[blockIdx.x] = ((lsum_lds[0] + lsum_lds[1]) +
                               (lsum_lds[2] + lsum_lds[3]));

    // ---- encodings: zero-fill this block's 64x512 slab with ALIGNED float4
    // (slab starts at global float index 1+16M+n0*512 == 1 mod 4 -> peel 3,
    // aligned float4 over [3, 32767), tail 1), then scatter the 64 ones.
    float* slab = out + 1 + (size_t)NROWS * DIM + (size_t)n0 * KCODES;
    if (t < 3) slab[t] = 0.0f;
    if (t == 0) slab[RPB * KCODES - 1] = 0.0f;
    {
        v4f* s4 = (v4f*)(slab + 3);          // 16B-aligned
        const v4f z = {0.f, 0.f, 0.f, 0.f};
        #pragma unroll 4
        for (int i = t; i < (RPB * KCODES - 4) / 4; i += TPB)  // 8191 stores
            s4[i] = z;
    }
    __syncthreads();   // drains vmcnt: zeros visible before ones (same CU/L1)
    if (t < RPB)
        slab[t * KCODES + idx_final[t]] = 1.0f;
}

__global__ __launch_bounds__(256) void vq_final(
    const float* __restrict__ partial, float* __restrict__ out)
{
    __shared__ float s[256];
    const int t = threadIdx.x;
    s[t] = (partial[t] + partial[t + 256]) + (partial[t + 512] + partial[t + 768]);
    __syncthreads();
    for (int off = 128; off; off >>= 1) {
        if (t < off) s[t] += s[t + off];
        __syncthreads();
    }
    if (t == 0) {
        const float m = s[0] / 4194304.0f;          // mean over B*H*W*D
        out[0] = __fadd_rn(m, __fmul_rn(0.25f, m)); // z_q + 0.25*z_e
    }
}

extern "C" void kernel_launch(void* const* d_in, const int* in_sizes, int n_in,
                              void* d_out, int out_size, void* d_ws, size_t ws_size,
                              hipStream_t stream) {
    const float* x = (const float*)d_in[0];
    const float* w = (const float*)d_in[1];
    float* out     = (float*)d_out;
    float* partial = (float*)d_ws;        // 1024 floats of scratch

    vq_main<<<NBLOCKS, TPB, 0, stream>>>(x, w, out, partial);
    vq_final<<<1, 256, 0, stream>>>(partial, out);
}